// Round 5
// baseline (1597.250 us; speedup 1.0000x reference)
//
#include <hip/hip_runtime.h>
#include <cstdint>
#include <cstddef>

typedef __bf16 bf16_t;
typedef __bf16 bf16x8 __attribute__((ext_vector_type(8)));
typedef __bf16 bf16x4 __attribute__((ext_vector_type(4)));
typedef float f32x4 __attribute__((ext_vector_type(4)));

#define A_TOTAL 262144
#define NMAP    131072

// ---------------- W1 slices f32 -> bf16 ------------------------------------
__global__ __launch_bounds__(256) void k_w1b16(
    const float* __restrict__ mW1, const float* __restrict__ sW1,
    bf16_t* __restrict__ dst) {
  int e = blockIdx.x * 256 + threadIdx.x;     // 0..262143
  int slice = e >> 16, idx = e & 65535;
  int n = idx >> 8, k = idx & 255;
  float v;
  switch (slice) {
    case 0:  v = mW1[n * 512 + k]; break;
    case 1:  v = mW1[n * 512 + 256 + k]; break;
    case 2:  v = sW1[n * 512 + k]; break;
    default: v = sW1[n * 512 + 256 + k]; break;
  }
  dst[e] = (bf16_t)v;
}

// ---------------- column partial sums of all_embeddings (f32x4) ------------
__global__ __launch_bounds__(256) void k_mean(const float* __restrict__ A,
                                              float* __restrict__ part) {
  __shared__ f32x4 sred[4][64];
  int t = threadIdx.x, b = blockIdx.x;        // 256 blocks x 512 rows
  int cg = t & 63, rs = t >> 6;
  const float* base = A + ((size_t)b * 512 + rs * 128) * 256 + cg * 4;
  f32x4 acc = {};
#pragma unroll 4
  for (int r = 0; r < 128; ++r)
    acc += *(const f32x4*)(base + (size_t)r * 256);
  sred[rs][cg] = acc;
  __syncthreads();
  if (t < 64) {
    f32x4 tot = sred[0][t] + sred[1][t] + sred[2][t] + sred[3][t];
    *(f32x4*)(part + b * 256 + t * 4) = tot;
  }
}

// ---------------- g -> query MLP -> q -> qk -> qw[2][4][256] f32 -----------
__global__ __launch_bounds__(256) void k_front(
    const float* __restrict__ meanPart,
    const float* __restrict__ qgW1, const float* __restrict__ qgb1,
    const float* __restrict__ qgW2, const float* __restrict__ qgb2,
    const float* __restrict__ Wq,  const float* __restrict__ bq,
    const float* __restrict__ Wk,
    const float* __restrict__ mW2, const float* __restrict__ sW2,
    float* __restrict__ qw) {
  __shared__ float g[256], h1[256], qry[256], qv[256];
  __shared__ float qks[4][256];
  int t = threadIdx.x;
  float s = 0.f;
  for (int b = 0; b < 256; ++b) s += meanPart[b * 256 + t];
  g[t] = s * (1.0f / 131072.0f);
  __syncthreads();
  {
    const f32x4* row = (const f32x4*)(qgW1 + (size_t)t * 256);
    float acc = 0.f;
    for (int k = 0; k < 64; ++k) {
      f32x4 w = row[k];
      acc += w[0] * g[4 * k] + w[1] * g[4 * k + 1] + w[2] * g[4 * k + 2] + w[3] * g[4 * k + 3];
    }
    h1[t] = fmaxf(acc + qgb1[t], 0.f);
  }
  __syncthreads();
  {
    const f32x4* row = (const f32x4*)(qgW2 + (size_t)t * 256);
    float acc = 0.f;
    for (int k = 0; k < 64; ++k) {
      f32x4 w = row[k];
      acc += w[0] * h1[4 * k] + w[1] * h1[4 * k + 1] + w[2] * h1[4 * k + 2] + w[3] * h1[4 * k + 3];
    }
    qry[t] = acc + qgb2[t];
  }
  __syncthreads();
  {
    const f32x4* row = (const f32x4*)(Wq + (size_t)t * 256);
    float acc = 0.f;
    for (int k = 0; k < 64; ++k) {
      f32x4 w = row[k];
      acc += w[0] * qry[4 * k] + w[1] * qry[4 * k + 1] + w[2] * qry[4 * k + 2] + w[3] * qry[4 * k + 3];
    }
    qv[t] = acc + bq[t];
  }
  __syncthreads();
  for (int h = 0; h < 4; ++h) {
    float acc = 0.f;
    for (int d = 0; d < 64; ++d) acc += qv[h * 64 + d] * Wk[(size_t)(h * 64 + d) * 256 + t];
    qks[h][t] = acc * 0.125f;
  }
  __syncthreads();
  for (int tab = 0; tab < 2; ++tab) {
    const float* W2 = tab ? sW2 : mW2;
    float acc0 = 0.f, acc1 = 0.f, acc2 = 0.f, acc3 = 0.f;
    for (int n = 0; n < 256; ++n) {
      float wv = W2[(size_t)n * 256 + t];
      acc0 += qks[0][n] * wv;
      acc1 += qks[1][n] * wv;
      acc2 += qks[2][n] * wv;
      acc3 += qks[3][n] * wv;
    }
    float* dst = qw + tab * 1024;
    dst[0 * 256 + t] = acc0;
    dst[1 * 256 + t] = acc1;
    dst[2 * 256 + t] = acc2;
    dst[3 * 256 + t] = acc3;
  }
}

// ---------------- GEMM (direct, merged halves, 34KB LDS, 4 blk/CU) ---------
__global__ __launch_bounds__(512, 8) void gemm_direct4(
    const float* __restrict__ A0, int M0, const bf16_t* __restrict__ W0,
    const float* __restrict__ b0, bf16_t* __restrict__ C0, int split,
    const float* __restrict__ A1, int M1, const bf16_t* __restrict__ W1,
    const float* __restrict__ b1, bf16_t* __restrict__ C1) {
  __shared__ __align__(16) bf16_t Xo[64][264];   // 33792 B
  int blk = blockIdx.x;
  const float* A; int M; const bf16_t* W; const float* bias; bf16_t* C; int bid;
  if (blk < split) { A = A0; M = M0; W = W0; bias = b0; C = C0; bid = blk; }
  else             { A = A1; M = M1; W = W1; bias = b1; C = C1; bid = blk - split; }
  int t = threadIdx.x;
  int w = t >> 6, lane = t & 63;
  int lm = lane & 15, q = lane >> 4;
  int m0 = bid * 128 + (w & 1) * 64;
  int c0 = (w >> 1) * 64;
  int rows[4];
#pragma unroll
  for (int i = 0; i < 4; ++i) {
    int m = m0 + i * 16 + lm;
    rows[i] = m < M ? m : M - 1;
  }
  f32x4 acc[4][4] = {};
#pragma unroll
  for (int kt = 0; kt < 8; ++kt) {
    int k0 = kt * 32 + q * 8;
    bf16x8 b[4];
#pragma unroll
    for (int j = 0; j < 4; ++j)
      b[j] = *(const bf16x8*)(W + (size_t)(c0 + j * 16 + lm) * 256 + k0);
#pragma unroll
    for (int i = 0; i < 4; ++i) {
      const float* src = A + (size_t)rows[i] * 256 + k0;
      f32x4 lo = *(const f32x4*)src;
      f32x4 hi = *(const f32x4*)(src + 4);
      bf16x8 a;
#pragma unroll
      for (int x = 0; x < 4; ++x) { a[x] = (bf16_t)lo[x]; a[x + 4] = (bf16_t)hi[x]; }
#pragma unroll
      for (int j = 0; j < 4; ++j)
        acc[i][j] = __builtin_amdgcn_mfma_f32_16x16x32_bf16(a, b[j], acc[i][j], 0, 0, 0);
    }
  }
  // two passes: waves with (w&1)==p stage their 64-row half, all copy out
#pragma unroll
  for (int p = 0; p < 2; ++p) {
    if (p) __syncthreads();            // prev copy reads done
    if ((w & 1) == p) {
#pragma unroll
      for (int j = 0; j < 4; ++j) {
        int col = c0 + j * 16 + lm;
        float bb = bias ? bias[col] : 0.f;
#pragma unroll
        for (int i = 0; i < 4; ++i)
#pragma unroll
          for (int r = 0; r < 4; ++r)
            Xo[i * 16 + q * 4 + r][col] = (bf16_t)(acc[i][j][r] + bb);
      }
    }
    __syncthreads();
    size_t tile0 = (size_t)bid * 128 + p * 64;
    const char* lds = (const char*)&Xo[0][0];
#pragma unroll
    for (int s = 0; s < 4; ++s) {
      int flat = s * 8192 + t * 16;
      int row = flat >> 9, colb = flat & 511;
      if (tile0 + (size_t)row < (size_t)M) {
        uint4 v = *(const uint4*)(lds + row * 528 + colb);
        *(uint4*)((char*)C + tile0 * 512 + (size_t)flat) = v;
      }
    }
  }
}

// ---------------- gather+relu -> X + scores + fused softmax stats ----------
// 4096 blocks; last block combines per-block (max,expsum) -> Mh, sinv.
__global__ __launch_bounds__(256) void k_gx(
    const bf16_t* __restrict__ Pa0, const bf16_t* __restrict__ Pb0,
    const int* __restrict__ idxA0, const int* __restrict__ idxB0,
    const bf16_t* __restrict__ Pa1, const bf16_t* __restrict__ Pb1,
    const int* __restrict__ idxA1, const int* __restrict__ idxB1,
    const float* __restrict__ qw,
    bf16_t* __restrict__ X, float* __restrict__ scores,
    float* __restrict__ partMax, float* __restrict__ partSum,
    int* __restrict__ cnt, float* __restrict__ Mh, float* __restrict__ sinv) {
  __shared__ float qs[4][256];
  __shared__ float sc[4][64];
  __shared__ float redM[256], redS[256];
  __shared__ int isLast;
  int t = threadIdx.x;
  int b = blockIdx.x;
  int rows0 = b * 64;
  int half = rows0 >= NMAP ? 1 : 0;
  const bf16_t* Pa = half ? Pa1 : Pa0;
  const bf16_t* Pb = half ? Pb1 : Pb0;
  const int* idxA = half ? idxA1 : idxA0;
  const int* idxB = half ? idxB1 : idxB0;
  int lrow0 = rows0 - half * NMAP;

  {
    f32x4 v = *(const f32x4*)(qw + half * 1024 + t * 4);
    *(f32x4*)&((float*)qs)[t * 4] = v;
  }

  int rg = t >> 5;          // row-in-group 0..7
  int cl = t & 31;          // 16B chunk lane
  int ia[8], ib[8];
#pragma unroll
  for (int it = 0; it < 8; ++it) {
    ia[it] = idxA[lrow0 + it * 8 + rg];
    ib[it] = idxB[lrow0 + it * 8 + rg];
  }
  __syncthreads();          // qs ready

#pragma unroll
  for (int it = 0; it < 8; ++it) {
    int rowg = it * 8 + rg;
    bf16x8 a8 = *(const bf16x8*)(Pa + (size_t)ia[it] * 256 + cl * 8);
    bf16x8 b8 = *(const bf16x8*)(Pb + (size_t)ib[it] * 256 + cl * 8);
    float x[8];
    bf16x8 xo;
#pragma unroll
    for (int e = 0; e < 8; ++e) {
      x[e] = fmaxf((float)a8[e] + (float)b8[e], 0.f);
      xo[e] = (bf16_t)x[e];
    }
    *(bf16x8*)(X + (size_t)(rows0 + rowg) * 256 + cl * 8) = xo;
    float p[4] = {0.f, 0.f, 0.f, 0.f};
#pragma unroll
    for (int h = 0; h < 4; ++h)
#pragma unroll
      for (int e = 0; e < 8; ++e)
        p[h] += x[e] * qs[h][cl * 8 + e];
#pragma unroll
    for (int h = 0; h < 4; ++h) {
#pragma unroll
      for (int o = 16; o > 0; o >>= 1) p[h] += __shfl_xor(p[h], o);
      if (cl == 0) sc[h][rowg] = p[h];
    }
  }
  __syncthreads();
  // scores write + per-block per-head (max, expsum)
  {
    int h = t >> 6, l = t & 63;
    float v = sc[h][l];
    scores[(size_t)h * A_TOTAL + rows0 + l] = v;
    float m = v;
#pragma unroll
    for (int o = 32; o > 0; o >>= 1) m = fmaxf(m, __shfl_xor(m, o));
    float s = __expf(v - m);
#pragma unroll
    for (int o = 32; o > 0; o >>= 1) s += __shfl_xor(s, o);
    if (l == 0) {
      partMax[h * 4096 + b] = m;
      partSum[h * 4096 + b] = s;
    }
  }
  __threadfence();
  __syncthreads();
  if (t == 0) isLast = (atomicAdd(cnt, 1) == (int)gridDim.x - 1);
  __syncthreads();
  if (!isLast) return;
  __threadfence();
  for (int h = 0; h < 4; ++h) {
    float m = -3.4e38f, s = 0.f;
    for (int i = t; i < 4096; i += 256) {
      float pm = partMax[h * 4096 + i], ps = partSum[h * 4096 + i];
      float nm = fmaxf(m, pm);
      s = s * __expf(m - nm) + ps * __expf(pm - nm);
      m = nm;
    }
    redM[t] = m; redS[t] = s;
    __syncthreads();
    for (int st = 128; st > 0; st >>= 1) {
      if (t < st) {
        float m2 = redM[t + st], s2 = redS[t + st];
        float nm = fmaxf(redM[t], m2);
        redS[t] = redS[t] * __expf(redM[t] - nm) + s2 * __expf(m2 - nm);
        redM[t] = nm;
      }
      __syncthreads();
    }
    if (t == 0) { Mh[h] = redM[0]; sinv[h] = 1.0f / redS[0]; }
    __syncthreads();
  }
}

// ---------------- y[half][h] = sum_a w[h,a]*X[a]; shalf = sum_a w ----------
__global__ __launch_bounds__(256) void k_u3(
    const bf16_t* __restrict__ X, const float* __restrict__ scores,
    const float* __restrict__ Mh, const float* __restrict__ invS,
    float* __restrict__ y, float* __restrict__ shalf) {
  __shared__ float wl[4][512];
  __shared__ float uloc[8][4][256];     // 32 KiB
  int t = threadIdx.x;
  int a0 = blockIdx.x * 512;            // 512 blocks x 512 rows
  int half = blockIdx.x >> 8;
#pragma unroll
  for (int i = 0; i < 8; ++i) {
    int e = i * 256 + t;
    int h = e >> 9, rr = e & 511;
    wl[h][rr] = __expf(scores[(size_t)h * A_TOTAL + a0 + rr] - Mh[h]) * invS[h];
  }
  __syncthreads();
  {
    int h = t >> 6, l = t & 63;
    float s = 0.f;
#pragma unroll
    for (int j = 0; j < 8; ++j) s += wl[h][l + j * 64];
#pragma unroll
    for (int o = 32; o > 0; o >>= 1) s += __shfl_xor(s, o);
    if (l == 0) atomicAdd(&shalf[half * 4 + h], s);
  }
  int tc = t & 31, rh = t >> 5;
  float acc[4][8] = {};
  for (int rr = 0; rr < 64; ++rr) {
    int al = rh * 64 + rr;
    bf16x8 kv = *(const bf16x8*)(X + (size_t)(a0 + al) * 256 + tc * 8);
    float f[8];
#pragma unroll
    for (int e = 0; e < 8; ++e) f[e] = (float)kv[e];
#pragma unroll
    for (int h = 0; h < 4; ++h) {
      float wv = wl[h][al];
#pragma unroll
      for (int e = 0; e < 8; ++e) acc[h][e] += wv * f[e];
    }
  }
#pragma unroll
  for (int h = 0; h < 4; ++h)
#pragma unroll
    for (int e = 0; e < 8; ++e) uloc[rh][h][tc * 8 + e] = acc[h][e];
  __syncthreads();
#pragma unroll
  for (int h = 0; h < 4; ++h) {
    float v = 0.f;
#pragma unroll
    for (int g = 0; g < 8; ++g) v += uloc[g][h][t];
    atomicAdd(&y[(half * 4 + h) * 256 + t], v);
  }
}

// ---------------- u[h][j]: one block per j (row-coalesced W2 reads) --------
__global__ __launch_bounds__(256) void k_u4(
    const float* __restrict__ y, const float* __restrict__ shalf,
    const float* __restrict__ mW2, const float* __restrict__ sW2,
    const float* __restrict__ mb2, const float* __restrict__ sb2,
    float* __restrict__ u) {
  __shared__ float wsum[4][4];
  int j = blockIdx.x, t = threadIdx.x;
  int w = t >> 6, lane = t & 63;
  float pm = mW2[(size_t)j * 256 + t], ps = sW2[(size_t)j * 256 + t];
  float p[4];
#pragma unroll
  for (int h = 0; h < 4; ++h)
    p[h] = y[(0 + h) * 256 + t] * pm + y[(4 + h) * 256 + t] * ps;
#pragma unroll
  for (int h = 0; h < 4; ++h)
#pragma unroll
    for (int o = 32; o > 0; o >>= 1) p[h] += __shfl_xor(p[h], o);
  if (lane == 0)
#pragma unroll
    for (int h = 0; h < 4; ++h) wsum[w][h] = p[h];
  __syncthreads();
  if (t < 4) {
    float tot = wsum[0][t] + wsum[1][t] + wsum[2][t] + wsum[3][t];
    u[t * 256 + j] = tot + shalf[t] * mb2[j] + shalf[4 + t] * sb2[j];
  }
}

// ---------------- ctx[j] = Wv[j].u_h + bv[j] -------------------------------
__global__ __launch_bounds__(256) void k_ctx(
    const float* __restrict__ u, const float* __restrict__ Wv,
    const float* __restrict__ bv, float* __restrict__ ctxv) {
  __shared__ float wsum[4];
  int j = blockIdx.x, t = threadIdx.x;
  int w = t >> 6, lane = t & 63;
  int h = j >> 6;
  float p = Wv[(size_t)j * 256 + t] * u[h * 256 + t];
#pragma unroll
  for (int o = 32; o > 0; o >>= 1) p += __shfl_xor(p, o);
  if (lane == 0) wsum[w] = p;
  __syncthreads();
  if (t == 0)
    ctxv[j] = wsum[0] + wsum[1] + wsum[2] + wsum[3] + bv[j];
}

// ---------------- att[j] = Wo[j].ctx + bo[j]; c01 atomics ------------------
__global__ __launch_bounds__(256) void k_att(
    const float* __restrict__ ctxv, const float* __restrict__ Wo,
    const float* __restrict__ bo,
    const float* __restrict__ mb2, const float* __restrict__ sb2,
    float* __restrict__ attv, float* __restrict__ c01) {
  __shared__ float wsum[4];
  int j = blockIdx.x, t = threadIdx.x;
  int w = t >> 6, lane = t & 63;
  float p = Wo[(size_t)j * 256 + t] * ctxv[t];
#pragma unroll
  for (int o = 32; o > 0; o >>= 1) p += __shfl_xor(p, o);
  if (lane == 0) wsum[w] = p;
  __syncthreads();
  if (t == 0) {
    float a = wsum[0] + wsum[1] + wsum[2] + wsum[3] + bo[j];
    attv[j] = a;
    atomicAdd(&c01[0], mb2[j] * a);
    atomicAdd(&c01[1], sb2[j] * a);
  }
}

// ---------------- z partials: 32 blocks x 16 W2-rows -----------------------
__global__ __launch_bounds__(256) void k_z(
    const float* __restrict__ mW2, const float* __restrict__ sW2,
    const float* __restrict__ attv, float* __restrict__ zpart) {
  __shared__ float as[16];
  int b = blockIdx.x, t = threadIdx.x;
  int tab = b >> 4, jc = b & 15;
  const float* W2 = tab ? sW2 : mW2;
  if (t < 16) as[t] = attv[jc * 16 + t];
  __syncthreads();
  float acc = 0.f;
#pragma unroll
  for (int i = 0; i < 16; ++i)
    acc += as[i] * W2[(size_t)(jc * 16 + i) * 256 + t];
  zpart[b * 256 + t] = acc;
}

// ---------------- z final: sum 16 partials, bf16 pad -----------------------
__global__ __launch_bounds__(256) void k_zfin(
    const float* __restrict__ zpart, bf16_t* __restrict__ zpad) {
  int t = threadIdx.x;
#pragma unroll
  for (int tab = 0; tab < 2; ++tab) {
    float s = 0.f;
#pragma unroll
    for (int i = 0; i < 16; ++i) s += zpart[(tab * 16 + i) * 256 + t];
    bf16_t* dst = zpad + (size_t)tab * 16 * 256;
    dst[t] = (bf16_t)s;
#pragma unroll
    for (int i = 1; i < 16; ++i) dst[i * 256 + t] = (bf16_t)0.f;
  }
}

// ---------------- logits + fused global softmax stats ----------------------
__global__ __launch_bounds__(256) void k_logits4(
    const bf16_t* __restrict__ X, const bf16_t* __restrict__ zpad,
    const float* __restrict__ c01,
    float* __restrict__ out_logits,
    float* __restrict__ blockMax, float* __restrict__ blockSum,
    int* __restrict__ cnt, float* __restrict__ Ml, float* __restrict__ invSl) {
  __shared__ float redm[4], reds[4];
  __shared__ float redM[256], redS[256];
  __shared__ int isLast;
  int t = threadIdx.x;
  int w = t >> 6, lane = t & 63;
  int lm = lane & 15, q = lane >> 4;
  int half = blockIdx.x >> 9;
  float c = c01[half];
  int m0 = blockIdx.x * 256 + w * 64;
  const bf16_t* zp = zpad + (size_t)half * 16 * 256;
  bf16x8 b[8];
#pragma unroll
  for (int kt = 0; kt < 8; ++kt)
    b[kt] = *(const bf16x8*)(zp + lm * 256 + kt * 32 + q * 8);
  f32x4 acc[4] = {};
#pragma unroll
  for (int i = 0; i < 4; ++i) {
    const bf16_t* arow = X + (size_t)(m0 + i * 16 + lm) * 256 + q * 8;
#pragma unroll
    for (int kt = 0; kt < 8; ++kt) {
      bf16x8 a = *(const bf16x8*)(arow + kt * 32);
      acc[i] = __builtin_amdgcn_mfma_f32_16x16x32_bf16(a, b[kt], acc[i], 0, 0, 0);
    }
  }
  float vals[16];
  float lmax = -3.4e38f;
  if (lm == 0) {
#pragma unroll
    for (int i = 0; i < 4; ++i) {
      f32x4 v4;
#pragma unroll
      for (int rr = 0; rr < 4; ++rr) {
        float v = acc[i][rr] + c;
        vals[i * 4 + rr] = v;
        v4[rr] = v;
        lmax = fmaxf(lmax, v);
      }
      *(f32x4*)(out_logits + m0 + i * 16 + q * 4) = v4;
    }
  }
  float m1 = fmaxf(lmax, __shfl_xor(lmax, 16));
  float m2 = fmaxf(m1, __shfl_xor(m1, 32));
  if (lane == 0) redm[w] = m2;
  __syncthreads();
  float mb = fmaxf(fmaxf(redm[0], redm[1]), fmaxf(redm[2], redm[3]));
  float s = 0.f;
  if (lm == 0) {
#pragma unroll
    for (int i2 = 0; i2 < 16; ++i2) s += __expf(vals[i2] - mb);
  }
  s += __shfl_xor(s, 16);
  s += __shfl_xor(s, 32);
  if (lane == 0) reds[w] = s;
  __syncthreads();
  if (t == 0) {
    blockMax[blockIdx.x] = mb;
    blockSum[blockIdx.x] = reds[0] + reds[1] + reds[2] + reds[3];
  }
  __threadfence();
  __syncthreads();
  if (t == 0) isLast = (atomicAdd(cnt, 1) == (int)gridDim.x - 1);
  __syncthreads();
  if (!isLast) return;
  __threadfence();
  float m = -3.4e38f, ssum = 0.f;
  for (int i = t; i < 1024; i += 256) {
    float pm = blockMax[i], ps = blockSum[i];
    float nm = fmaxf(m, pm);
    ssum = ssum * __expf(m - nm) + ps * __expf(pm - nm);
    m = nm;
  }
  redM[t] = m; redS[t] = ssum;
  __syncthreads();
  for (int st = 128; st > 0; st >>= 1) {
    if (t < st) {
      float mo = redM[t + st], so = redS[t + st];
      float nm = fmaxf(redM[t], mo);
      redS[t] = redS[t] * __expf(redM[t] - nm) + so * __expf(mo - nm);
      redM[t] = nm;
    }
    __syncthreads();
  }
  if (t == 0) { Ml[0] = redM[0]; invSl[0] = 1.0f / redS[0]; }
}

__global__ __launch_bounds__(256) void k_probs(const float* __restrict__ logits,
                                               const float* __restrict__ Ml,
                                               const float* __restrict__ invSl,
                                               float* __restrict__ probs) {
  int i = blockIdx.x * 256 + threadIdx.x;
  probs[i] = __expf(logits[i] - Ml[0]) * invSl[0];
}

// ===========================================================================
extern "C" void kernel_launch(void* const* d_in, const int* in_sizes, int n_in,
                              void* d_out, int out_size, void* d_ws, size_t ws_size,
                              hipStream_t stream) {
  const float* qubit_emb = (const float*)d_in[0];
  const float* qpu_emb   = (const float*)d_in[1];
  const float* gate_emb  = (const float*)d_in[2];
  const float* all_emb   = (const float*)d_in[3];
  const float* time_tab  = (const float*)d_in[4];
  const float* map_W1 = (const float*)d_in[5];
  const float* map_b1 = (const float*)d_in[6];
  const float* map_W2 = (const float*)d_in[7];
  const float* map_b2 = (const float*)d_in[8];
  const float* sch_W1 = (const float*)d_in[9];
  const float* sch_b1 = (const float*)d_in[10];
  const float* sch_W2 = (const float*)d_in[11];
  const float* sch_b2 = (const float*)d_in[12];
  const float* qg_W1 = (const float*)d_in[13];
  const float* qg_b1 = (const float*)d_in[14];
  const float* qg_W2 = (const float*)d_in[15];
  const float* qg_b2 = (const float*)d_in[16];
  const float* Wq = (const float*)d_in[17];
  const float* bq = (const float*)d_in[18];
  const float* Wk = (const float*)d_in[19];
  // d_in[20] = attn_bk: per-head constant, softmax-invariant -> unused
  const float* Wv = (const float*)d_in[21];
  const float* bv = (const float*)d_in[22];
  const float* Wo = (const float*)d_in[23];
  const float* bo = (const float*)d_in[24];
  const int* map_qubit  = (const int*)d_in[25];
  const int* map_qpu    = (const int*)d_in[26];
  const int* sched_gate = (const int*)d_in[27];
  const int* sched_time = (const int*)d_in[28];
  (void)in_sizes; (void)n_in; (void)out_size;

  char* ws = (char*)d_ws;
  size_t off = 0;
  auto alloc = [&](size_t b) { size_t r = off; off += (b + 255) & ~(size_t)255; return r; };
  size_t XB    = alloc((size_t)A_TOTAL * 256 * 2);   // bf16 relu activations X
  size_t PQ    = alloc((size_t)65536 * 256 * 2);     // bf16 qubit proj
  size_t PG    = alloc((size_t)65536 * 256 * 2);     // bf16 gate proj
  size_t PP    = alloc((size_t)128 * 256 * 2);       // bf16 qpu proj (+b1)
  size_t PT    = alloc((size_t)1024 * 256 * 2);      // bf16 time proj (+b1)
  size_t W1B   = alloc((size_t)4 * 65536 * 2);       // bf16 W1 slices
  size_t QW    = alloc((size_t)2 * 4 * 256 * 4);     // f32 qw
  size_t SCORE = alloc((size_t)4 * A_TOTAL * 4);     // f32 scores [4][A]
  size_t MPART = alloc((size_t)256 * 256 * 4);       // mean partials
  size_t ZPAD  = alloc((size_t)2 * 16 * 256 * 2);    // bf16 z padded
  size_t ZPART = alloc((size_t)32 * 256 * 4);        // f32 z partials
  size_t U     = alloc(4 * 256 * 4);
  size_t CTXV  = alloc(256 * 4);
  size_t ATTV  = alloc(256 * 4);
  size_t Y     = alloc(2 * 4 * 256 * 4);             // 8192 B (zeroed)
  size_t SH    = alloc(2 * 4 * 4);                   // +256 (zeroed)
  size_t C01   = alloc(2 * 4);                       // +256 (zeroed)
  size_t CNT   = alloc(2 * 4);                       // +256 (zeroed)
  size_t PMAX  = alloc(4 * 4096 * 4);
  size_t PSUM  = alloc(4 * 4096 * 4);
  size_t MH    = alloc(4 * 4);
  size_t SINV  = alloc(4 * 4);
  size_t BMAX  = alloc(1024 * 4);
  size_t BSUM  = alloc(1024 * 4);
  size_t ML    = alloc(4);
  size_t SLINV = alloc(4);
  if (off > ws_size) return;  // insufficient scratch -> loud validation fail

  bf16_t* xP     = (bf16_t*)(ws + XB);
  bf16_t* pqP    = (bf16_t*)(ws + PQ);
  bf16_t* pgP    = (bf16_t*)(ws + PG);
  bf16_t* ppP    = (bf16_t*)(ws + PP);
  bf16_t* ptP    = (bf16_t*)(ws + PT);
  bf16_t* w1bP   = (bf16_t*)(ws + W1B);
  float*  qwP    = (float*)(ws + QW);
  float*  scoreP = (float*)(ws + SCORE);
  float*  mpartP = (float*)(ws + MPART);
  bf16_t* zpadP  = (bf16_t*)(ws + ZPAD);
  float*  zpartP = (float*)(ws + ZPART);
  float*  uP     = (float*)(ws + U);
  float*  ctxvP  = (float*)(ws + CTXV);
  float*  attvP  = (float*)(ws + ATTV);
  float*  yP     = (float*)(ws + Y);
  float*  shP    = (float*)(ws + SH);
  float*  c01P   = (float*)(ws + C01);
  int*    cntP   = (int*)(ws + CNT);
  float*  pmaxP  = (float*)(ws + PMAX);
  float*  psumP  = (float*)(ws + PSUM);
  float*  mhP    = (float*)(ws + MH);
  float*  sinvP  = (float*)(ws + SINV);
  float*  bmaxP  = (float*)(ws + BMAX);
  float*  bsumP  = (float*)(ws + BSUM);
  float*  mlP    = (float*)(ws + ML);
  float*  slinvP = (float*)(ws + SLINV);

  float* probsOut  = (float*)d_out;
  float* logitsOut = probsOut + A_TOTAL;

  // zero y + shalf + c01 + counters (contiguous region)
  hipMemsetAsync(yP, 0, 8960, stream);

  k_w1b16<<<1024, 256, 0, stream>>>(map_W1, sch_W1, w1bP);
  k_mean<<<256, 256, 0, stream>>>(all_emb, mpartP);
  k_front<<<1, 256, 0, stream>>>(mpartP, qg_W1, qg_b1, qg_W2, qg_b2,
                                 Wq, bq, Wk, map_W2, sch_W2, qwP);

  // table projections: qubit+gate merged, qpu+time merged
  gemm_direct4<<<1024, 512, 0, stream>>>(
      qubit_emb, 65536, w1bP + 0 * 65536, nullptr, pqP, 512,
      gate_emb,  65536, w1bP + 2 * 65536, nullptr, pgP);
  gemm_direct4<<<9, 512, 0, stream>>>(
      qpu_emb, 64,   w1bP + 1 * 65536, map_b1, ppP, 1,
      time_tab, 1000, w1bP + 3 * 65536, sch_b1, ptP);

  // X + scores + fused per-head softmax stats (last block -> Mh, sinv)
  k_gx<<<4096, 256, 0, stream>>>(
      pqP, ppP, map_qubit, map_qpu,
      pgP, ptP, sched_gate, sched_time,
      qwP, xP, scoreP, pmaxP, psumP, cntP + 0, mhP, sinvP);

  // weighted X sums per half -> tail chain (all row-parallel)
  k_u3<<<512, 256, 0, stream>>>(xP, scoreP, mhP, sinvP, yP, shP);
  k_u4<<<256, 256, 0, stream>>>(yP, shP, map_W2, sch_W2, map_b2, sch_b2, uP);
  k_ctx<<<256, 256, 0, stream>>>(uP, Wv, bv, ctxvP);
  k_att<<<256, 256, 0, stream>>>(ctxvP, Wo, bo, map_b2, sch_b2, attvP, c01P);
  k_z<<<32, 256, 0, stream>>>(map_W2, sch_W2, attvP, zpartP);
  k_zfin<<<1, 256, 0, stream>>>(zpartP, zpadP);

  // logits + fused global softmax stats (last block -> Ml, invSl)
  k_logits4<<<1024, 256, 0, stream>>>(xP, zpadP, c01P, logitsOut,
                                      bmaxP, bsumP, cntP + 1, mlP, slinvP);
  k_probs<<<1024, 256, 0, stream>>>(logitsOut, mlP, slinvP, probsOut);
}

// Round 7
// 674.223 us; speedup vs baseline: 2.3690x; 2.3690x over previous
//
#include <hip/hip_runtime.h>
#include <cstdint>
#include <cstddef>

typedef __bf16 bf16_t;
typedef __bf16 bf16x8 __attribute__((ext_vector_type(8)));
typedef __bf16 bf16x4 __attribute__((ext_vector_type(4)));
typedef float f32x4 __attribute__((ext_vector_type(4)));

#define A_TOTAL 262144
#define NMAP    131072

// ---------------- W1 slices f32 -> bf16 ------------------------------------
__global__ __launch_bounds__(256) void k_w1b16(
    const float* __restrict__ mW1, const float* __restrict__ sW1,
    bf16_t* __restrict__ dst) {
  int e = blockIdx.x * 256 + threadIdx.x;     // 0..262143
  int slice = e >> 16, idx = e & 65535;
  int n = idx >> 8, k = idx & 255;
  float v;
  switch (slice) {
    case 0:  v = mW1[n * 512 + k]; break;
    case 1:  v = mW1[n * 512 + 256 + k]; break;
    case 2:  v = sW1[n * 512 + k]; break;
    default: v = sW1[n * 512 + 256 + k]; break;
  }
  dst[e] = (bf16_t)v;
}

// ---------------- column partial sums of all_embeddings (2048 blocks) ------
__global__ __launch_bounds__(256) void k_mean(const float* __restrict__ A,
                                              float* __restrict__ part) {
  __shared__ f32x4 sred[4][64];
  int t = threadIdx.x, b = blockIdx.x;        // 2048 blocks x 64 rows
  int cg = t & 63, rs = t >> 6;
  const float* base = A + ((size_t)b * 64 + rs * 16) * 256 + cg * 4;
  f32x4 acc = {};
#pragma unroll
  for (int r = 0; r < 16; ++r)
    acc += *(const f32x4*)(base + (size_t)r * 256);
  sred[rs][cg] = acc;
  __syncthreads();
  if (t < 64) {
    f32x4 tot = sred[0][t] + sred[1][t] + sred[2][t] + sred[3][t];
    *(f32x4*)(part + (size_t)b * 256 + t * 4) = tot;
  }
}

// ---------------- reduce 2048 partials -> 16 -------------------------------
__global__ __launch_bounds__(256) void k_mean2(const float* __restrict__ part,
                                               float* __restrict__ part2) {
  int t = threadIdx.x, j = blockIdx.x;        // 16 blocks x 128 rows
  const float* base = part + (size_t)j * 128 * 256 + t;
  float s = 0.f;
  for (int i = 0; i < 128; ++i) s += base[(size_t)i * 256];
  part2[j * 256 + t] = s;
}

// ---------------- g -> query MLP -> q -> qk -> qw[2][4][256] f32 -----------
__global__ __launch_bounds__(256) void k_front(
    const float* __restrict__ part2,
    const float* __restrict__ qgW1, const float* __restrict__ qgb1,
    const float* __restrict__ qgW2, const float* __restrict__ qgb2,
    const float* __restrict__ Wq,  const float* __restrict__ bq,
    const float* __restrict__ Wk,
    const float* __restrict__ mW2, const float* __restrict__ sW2,
    float* __restrict__ qw) {
  __shared__ float g[256], h1[256], qry[256], qv[256];
  __shared__ float qks[4][256];
  int t = threadIdx.x;
  float s = 0.f;
#pragma unroll
  for (int b = 0; b < 16; ++b) s += part2[b * 256 + t];
  g[t] = s * (1.0f / 131072.0f);
  __syncthreads();
  {
    const f32x4* row = (const f32x4*)(qgW1 + (size_t)t * 256);
    float acc = 0.f;
    for (int k = 0; k < 64; ++k) {
      f32x4 w = row[k];
      acc += w[0] * g[4 * k] + w[1] * g[4 * k + 1] + w[2] * g[4 * k + 2] + w[3] * g[4 * k + 3];
    }
    h1[t] = fmaxf(acc + qgb1[t], 0.f);
  }
  __syncthreads();
  {
    const f32x4* row = (const f32x4*)(qgW2 + (size_t)t * 256);
    float acc = 0.f;
    for (int k = 0; k < 64; ++k) {
      f32x4 w = row[k];
      acc += w[0] * h1[4 * k] + w[1] * h1[4 * k + 1] + w[2] * h1[4 * k + 2] + w[3] * h1[4 * k + 3];
    }
    qry[t] = acc + qgb2[t];
  }
  __syncthreads();
  {
    const f32x4* row = (const f32x4*)(Wq + (size_t)t * 256);
    float acc = 0.f;
    for (int k = 0; k < 64; ++k) {
      f32x4 w = row[k];
      acc += w[0] * qry[4 * k] + w[1] * qry[4 * k + 1] + w[2] * qry[4 * k + 2] + w[3] * qry[4 * k + 3];
    }
    qv[t] = acc + bq[t];
  }
  __syncthreads();
  for (int h = 0; h < 4; ++h) {
    float acc = 0.f;
    for (int d = 0; d < 64; ++d) acc += qv[h * 64 + d] * Wk[(size_t)(h * 64 + d) * 256 + t];
    qks[h][t] = acc * 0.125f;
  }
  __syncthreads();
  for (int tab = 0; tab < 2; ++tab) {
    const float* W2 = tab ? sW2 : mW2;
    float acc0 = 0.f, acc1 = 0.f, acc2 = 0.f, acc3 = 0.f;
    for (int n = 0; n < 256; ++n) {
      float wv = W2[(size_t)n * 256 + t];
      acc0 += qks[0][n] * wv;
      acc1 += qks[1][n] * wv;
      acc2 += qks[2][n] * wv;
      acc3 += qks[3][n] * wv;
    }
    float* dst = qw + tab * 1024;
    dst[0 * 256 + t] = acc0;
    dst[1 * 256 + t] = acc1;
    dst[2 * 256 + t] = acc2;
    dst[3 * 256 + t] = acc3;
  }
}

// ---------------- GEMM (direct, merged 2 problem halves) -------------------
__global__ __launch_bounds__(512, 4) void gemm_direct3(
    const float* __restrict__ A0, int M0, const bf16_t* __restrict__ W0,
    const float* __restrict__ b0, bf16_t* __restrict__ C0, int split,
    const float* __restrict__ A1, int M1, const bf16_t* __restrict__ W1,
    const float* __restrict__ b1, bf16_t* __restrict__ C1) {
  __shared__ __align__(16) bf16_t Xo[128][264];   // 67584 B
  int blk = blockIdx.x;
  const float* A; int M; const bf16_t* W; const float* bias; bf16_t* C; int bid;
  if (blk < split) { A = A0; M = M0; W = W0; bias = b0; C = C0; bid = blk; }
  else             { A = A1; M = M1; W = W1; bias = b1; C = C1; bid = blk - split; }
  int t = threadIdx.x;
  int w = t >> 6, lane = t & 63;
  int lm = lane & 15, q = lane >> 4;
  int mloc0 = (w & 1) * 64;
  int m0 = bid * 128 + mloc0;
  int c0 = (w >> 1) * 64;
  int rows[4];
#pragma unroll
  for (int i = 0; i < 4; ++i) {
    int m = m0 + i * 16 + lm;
    rows[i] = m < M ? m : M - 1;
  }
  f32x4 acc[4][4] = {};
#pragma unroll
  for (int kt = 0; kt < 8; ++kt) {
    int k0 = kt * 32 + q * 8;
    bf16x8 b[4];
#pragma unroll
    for (int j = 0; j < 4; ++j)
      b[j] = *(const bf16x8*)(W + (size_t)(c0 + j * 16 + lm) * 256 + k0);
#pragma unroll
    for (int i = 0; i < 4; ++i) {
      const float* src = A + (size_t)rows[i] * 256 + k0;
      f32x4 lo = *(const f32x4*)src;
      f32x4 hi = *(const f32x4*)(src + 4);
      bf16x8 a;
#pragma unroll
      for (int x = 0; x < 4; ++x) { a[x] = (bf16_t)lo[x]; a[x + 4] = (bf16_t)hi[x]; }
#pragma unroll
      for (int j = 0; j < 4; ++j)
        acc[i][j] = __builtin_amdgcn_mfma_f32_16x16x32_bf16(a, b[j], acc[i][j], 0, 0, 0);
    }
  }
#pragma unroll
  for (int j = 0; j < 4; ++j) {
    int col = c0 + j * 16 + lm;
    float bb = bias ? bias[col] : 0.f;
#pragma unroll
    for (int i = 0; i < 4; ++i)
#pragma unroll
      for (int r = 0; r < 4; ++r)
        Xo[mloc0 + i * 16 + q * 4 + r][col] = (bf16_t)(acc[i][j][r] + bb);
  }
  __syncthreads();
  size_t tile0 = (size_t)bid * 128;
  const char* lds = (const char*)&Xo[0][0];
#pragma unroll
  for (int s = 0; s < 8; ++s) {
    int flat = s * 8192 + t * 16;
    int row = flat >> 9, colb = flat & 511;
    if (tile0 + (size_t)row < (size_t)M) {
      uint4 v = *(const uint4*)(lds + row * 528 + colb);
      *(uint4*)((char*)C + tile0 * 512 + (size_t)flat) = v;
    }
  }
}

// ---------------- gather+relu -> X + scores (q in registers, no LDS q) -----
// 4096 blocks x 64 rows; 32 lanes per row (16B chunks).
__global__ __launch_bounds__(256) void k_gx(
    const bf16_t* __restrict__ Pa0, const bf16_t* __restrict__ Pb0,
    const int* __restrict__ idxA0, const int* __restrict__ idxB0,
    const bf16_t* __restrict__ Pa1, const bf16_t* __restrict__ Pb1,
    const int* __restrict__ idxA1, const int* __restrict__ idxB1,
    const float* __restrict__ qw,
    bf16_t* __restrict__ X, float* __restrict__ scores,
    float* __restrict__ partMax) {
  __shared__ float sc[4][64];
  int t = threadIdx.x;
  int b = blockIdx.x;
  int rows0 = b * 64;
  int half = rows0 >= NMAP ? 1 : 0;
  const bf16_t* Pa = half ? Pa1 : Pa0;
  const bf16_t* Pb = half ? Pb1 : Pb0;
  const int* idxA = half ? idxA1 : idxA0;
  const int* idxB = half ? idxB1 : idxB0;
  int lrow0 = rows0 - half * NMAP;

  int rg = t >> 5;          // row-in-group 0..7
  int cl = t & 31;          // 16B chunk lane
  // q slice for this thread's 8 columns, held in registers (L2-hot 8KB qw)
  f32x4 q4[4][2];
#pragma unroll
  for (int h = 0; h < 4; ++h) {
    q4[h][0] = *(const f32x4*)(qw + half * 1024 + h * 256 + cl * 8);
    q4[h][1] = *(const f32x4*)(qw + half * 1024 + h * 256 + cl * 8 + 4);
  }
  // preload all indices (16 scalar loads in flight)
  int ia[8], ib[8];
#pragma unroll
  for (int it = 0; it < 8; ++it) {
    ia[it] = idxA[lrow0 + it * 8 + rg];
    ib[it] = idxB[lrow0 + it * 8 + rg];
  }

#pragma unroll
  for (int it = 0; it < 8; ++it) {
    int rowg = it * 8 + rg;
    bf16x8 a8 = *(const bf16x8*)(Pa + (size_t)ia[it] * 256 + cl * 8);
    bf16x8 b8 = *(const bf16x8*)(Pb + (size_t)ib[it] * 256 + cl * 8);
    float x[8];
    bf16x8 xo;
#pragma unroll
    for (int e = 0; e < 8; ++e) {
      x[e] = fmaxf((float)a8[e] + (float)b8[e], 0.f);
      xo[e] = (bf16_t)x[e];
    }
    *(bf16x8*)(X + (size_t)(rows0 + rowg) * 256 + cl * 8) = xo;
    float p[4] = {0.f, 0.f, 0.f, 0.f};
#pragma unroll
    for (int h = 0; h < 4; ++h)
#pragma unroll
      for (int e = 0; e < 8; ++e)
        p[h] += x[e] * q4[h][e >> 2][e & 3];
#pragma unroll
    for (int h = 0; h < 4; ++h) {
#pragma unroll
      for (int o = 16; o > 0; o >>= 1) p[h] += __shfl_xor(p[h], o);
      if (cl == 0) sc[h][rowg] = p[h];
    }
  }
  __syncthreads();
  // scores write (coalesced per head) + per-block per-head max
  {
    int h = t >> 6, l = t & 63;
    float v = sc[h][l];
    scores[(size_t)h * A_TOTAL + rows0 + l] = v;
    float m = v;
#pragma unroll
    for (int o = 32; o > 0; o >>= 1) m = fmaxf(m, __shfl_xor(m, o));
    if (l == 0) partMax[h * 4096 + b] = m;
  }
}

// ---------------- per-head max over 4096 tile partials ---------------------
__global__ __launch_bounds__(256) void k_smax2(const float* __restrict__ pM,
                                               float* __restrict__ Mh) {
  int t = threadIdx.x;
  __shared__ float red[256];
  for (int h = 0; h < 4; ++h) {
    float m = -3.4e38f;
    for (int i = t; i < 4096; i += 256) m = fmaxf(m, pM[h * 4096 + i]);
    red[t] = m;
    __syncthreads();
    for (int s = 128; s > 0; s >>= 1) {
      if (t < s) red[t] = fmaxf(red[t], red[t + s]);
      __syncthreads();
    }
    if (t == 0) Mh[h] = red[0];
    __syncthreads();
  }
}

__global__ __launch_bounds__(256) void k_ssum(const float* __restrict__ scores,
                                              const float* __restrict__ Mh,
                                              float* __restrict__ part) {
  int b = blockIdx.x, t = threadIdx.x;    // 256 blocks, head = b>>6
  float m = Mh[b >> 6];
  const float* base = scores + (size_t)b * 4096;
  float s = 0.f;
  for (int i = 0; i < 16; ++i) s += __expf(base[i * 256 + t] - m);
  __shared__ float red[256];
  red[t] = s;
  __syncthreads();
  for (int st = 128; st > 0; st >>= 1) {
    if (t < st) red[t] += red[t + st];
    __syncthreads();
  }
  if (t == 0) part[b] = red[0];
}

__global__ __launch_bounds__(256) void k_ssum2(const float* __restrict__ part,
                                               float* __restrict__ invS) {
  int t = threadIdx.x;
  __shared__ float red[256];
  red[t] = part[t];
  __syncthreads();
  for (int s = 32; s > 0; s >>= 1) {
    if ((t & 63) < s) red[t] += red[t + s];
    __syncthreads();
  }
  if ((t & 63) == 0) invS[t >> 6] = 1.0f / red[t];
}

// ---------------- y[half][h] = sum_a w[h,a]*X[a]; shalf = sum_a w ----------
__global__ __launch_bounds__(256) void k_u3(
    const bf16_t* __restrict__ X, const float* __restrict__ scores,
    const float* __restrict__ Mh, const float* __restrict__ invS,
    float* __restrict__ y, float* __restrict__ shalf) {
  __shared__ float wl[4][512];
  __shared__ float uloc[8][4][256];     // 32 KiB
  int t = threadIdx.x;
  int a0 = blockIdx.x * 512;            // 512 blocks x 512 rows
  int half = blockIdx.x >> 8;
#pragma unroll
  for (int i = 0; i < 8; ++i) {
    int e = i * 256 + t;
    int h = e >> 9, rr = e & 511;
    wl[h][rr] = __expf(scores[(size_t)h * A_TOTAL + a0 + rr] - Mh[h]) * invS[h];
  }
  __syncthreads();
  {
    int h = t >> 6, l = t & 63;
    float s = 0.f;
#pragma unroll
    for (int j = 0; j < 8; ++j) s += wl[h][l + j * 64];
#pragma unroll
    for (int o = 32; o > 0; o >>= 1) s += __shfl_xor(s, o);
    if (l == 0) atomicAdd(&shalf[half * 4 + h], s);
  }
  int tc = t & 31, rh = t >> 5;
  float acc[4][8] = {};
  for (int rr = 0; rr < 64; ++rr) {
    int al = rh * 64 + rr;
    bf16x8 kv = *(const bf16x8*)(X + (size_t)(a0 + al) * 256 + tc * 8);
    float f[8];
#pragma unroll
    for (int e = 0; e < 8; ++e) f[e] = (float)kv[e];
#pragma unroll
    for (int h = 0; h < 4; ++h) {
      float wv = wl[h][al];
#pragma unroll
      for (int e = 0; e < 8; ++e) acc[h][e] += wv * f[e];
    }
  }
#pragma unroll
  for (int h = 0; h < 4; ++h)
#pragma unroll
    for (int e = 0; e < 8; ++e) uloc[rh][h][tc * 8 + e] = acc[h][e];
  __syncthreads();
#pragma unroll
  for (int h = 0; h < 4; ++h) {
    float v = 0.f;
#pragma unroll
    for (int g = 0; g < 8; ++g) v += uloc[g][h][t];
    atomicAdd(&y[(half * 4 + h) * 256 + t], v);
  }
}

// ---------------- u[h][j]: one block per j (row-coalesced W2 reads) --------
__global__ __launch_bounds__(256) void k_u4(
    const float* __restrict__ y, const float* __restrict__ shalf,
    const float* __restrict__ mW2, const float* __restrict__ sW2,
    const float* __restrict__ mb2, const float* __restrict__ sb2,
    float* __restrict__ u) {
  __shared__ float wsum[4][4];
  int j = blockIdx.x, t = threadIdx.x;
  int w = t >> 6, lane = t & 63;
  float pm = mW2[(size_t)j * 256 + t], ps = sW2[(size_t)j * 256 + t];
  float p[4];
#pragma unroll
  for (int h = 0; h < 4; ++h)
    p[h] = y[(0 + h) * 256 + t] * pm + y[(4 + h) * 256 + t] * ps;
#pragma unroll
  for (int h = 0; h < 4; ++h)
#pragma unroll
    for (int o = 32; o > 0; o >>= 1) p[h] += __shfl_xor(p[h], o);
  if (lane == 0)
#pragma unroll
    for (int h = 0; h < 4; ++h) wsum[w][h] = p[h];
  __syncthreads();
  if (t < 4) {
    float tot = wsum[0][t] + wsum[1][t] + wsum[2][t] + wsum[3][t];
    u[t * 256 + j] = tot + shalf[t] * mb2[j] + shalf[4 + t] * sb2[j];
  }
}

// ---------------- ctx[j] = Wv[j].u_h + bv[j] -------------------------------
__global__ __launch_bounds__(256) void k_ctx(
    const float* __restrict__ u, const float* __restrict__ Wv,
    const float* __restrict__ bv, float* __restrict__ ctxv) {
  __shared__ float wsum[4];
  int j = blockIdx.x, t = threadIdx.x;
  int w = t >> 6, lane = t & 63;
  int h = j >> 6;
  float p = Wv[(size_t)j * 256 + t] * u[h * 256 + t];
#pragma unroll
  for (int o = 32; o > 0; o >>= 1) p += __shfl_xor(p, o);
  if (lane == 0) wsum[w] = p;
  __syncthreads();
  if (t == 0)
    ctxv[j] = wsum[0] + wsum[1] + wsum[2] + wsum[3] + bv[j];
}

// ---------------- att[j] = Wo[j].ctx + bo[j]; c01 atomics ------------------
__global__ __launch_bounds__(256) void k_att(
    const float* __restrict__ ctxv, const float* __restrict__ Wo,
    const float* __restrict__ bo,
    const float* __restrict__ mb2, const float* __restrict__ sb2,
    float* __restrict__ attv, float* __restrict__ c01) {
  __shared__ float wsum[4];
  int j = blockIdx.x, t = threadIdx.x;
  int w = t >> 6, lane = t & 63;
  float p = Wo[(size_t)j * 256 + t] * ctxv[t];
#pragma unroll
  for (int o = 32; o > 0; o >>= 1) p += __shfl_xor(p, o);
  if (lane == 0) wsum[w] = p;
  __syncthreads();
  if (t == 0) {
    float a = wsum[0] + wsum[1] + wsum[2] + wsum[3] + bo[j];
    attv[j] = a;
    atomicAdd(&c01[0], mb2[j] * a);
    atomicAdd(&c01[1], sb2[j] * a);
  }
}

// ---------------- z partials: 32 blocks x 16 W2-rows -----------------------
__global__ __launch_bounds__(256) void k_z(
    const float* __restrict__ mW2, const float* __restrict__ sW2,
    const float* __restrict__ attv, float* __restrict__ zpart) {
  __shared__ float as[16];
  int b = blockIdx.x, t = threadIdx.x;
  int tab = b >> 4, jc = b & 15;
  const float* W2 = tab ? sW2 : mW2;
  if (t < 16) as[t] = attv[jc * 16 + t];
  __syncthreads();
  float acc = 0.f;
#pragma unroll
  for (int i = 0; i < 16; ++i)
    acc += as[i] * W2[(size_t)(jc * 16 + i) * 256 + t];
  zpart[b * 256 + t] = acc;
}

// ---------------- z final: sum 16 partials, bf16 pad -----------------------
__global__ __launch_bounds__(256) void k_zfin(
    const float* __restrict__ zpart, bf16_t* __restrict__ zpad) {
  int t = threadIdx.x;
#pragma unroll
  for (int tab = 0; tab < 2; ++tab) {
    float s = 0.f;
#pragma unroll
    for (int i = 0; i < 16; ++i) s += zpart[(tab * 16 + i) * 256 + t];
    bf16_t* dst = zpad + (size_t)tab * 16 * 256;
    dst[t] = (bf16_t)s;
#pragma unroll
    for (int i = 1; i < 16; ++i) dst[i * 256 + t] = (bf16_t)0.f;
  }
}

// ---------------- logits[a] = X[a].z_half + c_half (MFMA) + block max ------
__global__ __launch_bounds__(256) void k_logits3(
    const bf16_t* __restrict__ X, const bf16_t* __restrict__ zpad,
    const float* __restrict__ c01,
    float* __restrict__ out_logits, float* __restrict__ blockMax) {
  int t = threadIdx.x;
  int w = t >> 6, lane = t & 63;
  int lm = lane & 15, q = lane >> 4;
  int half = blockIdx.x >> 9;
  float c = c01[half];
  int m0 = blockIdx.x * 256 + w * 64;
  const bf16_t* zp = zpad + (size_t)half * 16 * 256;
  bf16x8 b[8];
#pragma unroll
  for (int kt = 0; kt < 8; ++kt)
    b[kt] = *(const bf16x8*)(zp + lm * 256 + kt * 32 + q * 8);
  f32x4 acc[4] = {};
#pragma unroll
  for (int i = 0; i < 4; ++i) {
    const bf16_t* arow = X + (size_t)(m0 + i * 16 + lm) * 256 + q * 8;
#pragma unroll
    for (int kt = 0; kt < 8; ++kt) {
      bf16x8 a = *(const bf16x8*)(arow + kt * 32);
      acc[i] = __builtin_amdgcn_mfma_f32_16x16x32_bf16(a, b[kt], acc[i], 0, 0, 0);
    }
  }
  float lmax = -3.4e38f;
  if (lm == 0) {
#pragma unroll
    for (int i = 0; i < 4; ++i) {
      f32x4 v4;
#pragma unroll
      for (int rr = 0; rr < 4; ++rr) {
        float v = acc[i][rr] + c;
        v4[rr] = v;
        lmax = fmaxf(lmax, v);
      }
      *(f32x4*)(out_logits + m0 + i * 16 + q * 4) = v4;
    }
  }
  float m1 = fmaxf(lmax, __shfl_xor(lmax, 16));
  float m2 = fmaxf(m1, __shfl_xor(m1, 32));
  __shared__ float red[4];
  if (lane == 0) red[w] = m2;
  __syncthreads();
  if (t == 0)
    blockMax[blockIdx.x] = fmaxf(fmaxf(red[0], red[1]), fmaxf(red[2], red[3]));
}

__global__ __launch_bounds__(256) void k_lred1(const float* __restrict__ bm,
                                               float* __restrict__ Ml) {
  int t = threadIdx.x;
  float m = -3.4e38f;
  for (int i = t; i < 1024; i += 256) m = fmaxf(m, bm[i]);
  __shared__ float red[256];
  red[t] = m;
  __syncthreads();
  for (int s = 128; s > 0; s >>= 1) {
    if (t < s) red[t] = fmaxf(red[t], red[t + s]);
    __syncthreads();
  }
  if (t == 0) Ml[0] = red[0];
}

__global__ __launch_bounds__(256) void k_lsum(const float* __restrict__ logits,
                                              const float* __restrict__ Ml,
                                              float* __restrict__ part) {
  int t = threadIdx.x, b = blockIdx.x;   // 512 blocks x 512 elems
  float m = Ml[0];
  float s = __expf(logits[b * 512 + t] - m) + __expf(logits[b * 512 + 256 + t] - m);
  __shared__ float red[256];
  red[t] = s;
  __syncthreads();
  for (int st = 128; st > 0; st >>= 1) {
    if (t < st) red[t] += red[t + st];
    __syncthreads();
  }
  if (t == 0) part[b] = red[0];
}

__global__ __launch_bounds__(256) void k_lred2(const float* __restrict__ part,
                                               float* __restrict__ invSl) {
  int t = threadIdx.x;
  float s = part[t] + part[t + 256];
  __shared__ float red[256];
  red[t] = s;
  __syncthreads();
  for (int st = 128; st > 0; st >>= 1) {
    if (t < st) red[t] += red[t + st];
    __syncthreads();
  }
  if (t == 0) invSl[0] = 1.0f / red[0];
}

__global__ __launch_bounds__(256) void k_probs(const float* __restrict__ logits,
                                               const float* __restrict__ Ml,
                                               const float* __restrict__ invSl,
                                               float* __restrict__ probs) {
  int i = blockIdx.x * 256 + threadIdx.x;
  probs[i] = __expf(logits[i] - Ml[0]) * invSl[0];
}

// ===========================================================================
extern "C" void kernel_launch(void* const* d_in, const int* in_sizes, int n_in,
                              void* d_out, int out_size, void* d_ws, size_t ws_size,
                              hipStream_t stream) {
  const float* qubit_emb = (const float*)d_in[0];
  const float* qpu_emb   = (const float*)d_in[1];
  const float* gate_emb  = (const float*)d_in[2];
  const float* all_emb   = (const float*)d_in[3];
  const float* time_tab  = (const float*)d_in[4];
  const float* map_W1 = (const float*)d_in[5];
  const float* map_b1 = (const float*)d_in[6];
  const float* map_W2 = (const float*)d_in[7];
  const float* map_b2 = (const float*)d_in[8];
  const float* sch_W1 = (const float*)d_in[9];
  const float* sch_b1 = (const float*)d_in[10];
  const float* sch_W2 = (const float*)d_in[11];
  const float* sch_b2 = (const float*)d_in[12];
  const float* qg_W1 = (const float*)d_in[13];
  const float* qg_b1 = (const float*)d_in[14];
  const float* qg_W2 = (const float*)d_in[15];
  const float* qg_b2 = (const float*)d_in[16];
  const float* Wq = (const float*)d_in[17];
  const float* bq = (const float*)d_in[18];
  const float* Wk = (const float*)d_in[19];
  // d_in[20] = attn_bk: per-head constant, softmax-invariant -> unused
  const float* Wv = (const float*)d_in[21];
  const float* bv = (const float*)d_in[22];
  const float* Wo = (const float*)d_in[23];
  const float* bo = (const float*)d_in[24];
  const int* map_qubit  = (const int*)d_in[25];
  const int* map_qpu    = (const int*)d_in[26];
  const int* sched_gate = (const int*)d_in[27];
  const int* sched_time = (const int*)d_in[28];
  (void)in_sizes; (void)n_in; (void)out_size;

  char* ws = (char*)d_ws;
  size_t off = 0;
  auto alloc = [&](size_t b) { size_t r = off; off += (b + 255) & ~(size_t)255; return r; };
  size_t XB    = alloc((size_t)A_TOTAL * 256 * 2);   // bf16 relu activations X
  size_t PQ    = alloc((size_t)65536 * 256 * 2);     // bf16 qubit proj
  size_t PG    = alloc((size_t)65536 * 256 * 2);     // bf16 gate proj
  size_t PP    = alloc((size_t)128 * 256 * 2);       // bf16 qpu proj (+b1)
  size_t PT    = alloc((size_t)1024 * 256 * 2);      // bf16 time proj (+b1)
  size_t W1B   = alloc((size_t)4 * 65536 * 2);       // bf16 W1 slices
  size_t QW    = alloc((size_t)2 * 4 * 256 * 4);     // f32 qw
  size_t SCORE = alloc((size_t)4 * A_TOTAL * 4);     // f32 scores [4][A]
  size_t MPART = alloc((size_t)2048 * 256 * 4);      // mean partials
  size_t MPRT2 = alloc((size_t)16 * 256 * 4);        // mean partials 2
  size_t ZPAD  = alloc((size_t)2 * 16 * 256 * 2);    // bf16 z padded
  size_t ZPART = alloc((size_t)32 * 256 * 4);        // f32 z partials
  size_t U     = alloc(4 * 256 * 4);
  size_t CTXV  = alloc(256 * 4);
  size_t ATTV  = alloc(256 * 4);
  size_t Y     = alloc(2 * 4 * 256 * 4);             // 8192 B (zeroed)
  size_t SH    = alloc(2 * 4 * 4);                   // +256 (zeroed)
  size_t C01   = alloc(2 * 4);                       // +256 (zeroed)
  size_t PMAX  = alloc(4 * 4096 * 4);
  size_t MH    = alloc(4 * 4);
  size_t SINV  = alloc(4 * 4);
  size_t SPART = alloc(256 * 4);
  size_t BMAX  = alloc(1024 * 4);
  size_t ML    = alloc(4);
  size_t SLINV = alloc(4);
  size_t LPART = alloc(512 * 4);
  if (off > ws_size) return;  // insufficient scratch -> loud validation fail

  bf16_t* xP     = (bf16_t*)(ws + XB);
  bf16_t* pqP    = (bf16_t*)(ws + PQ);
  bf16_t* pgP    = (bf16_t*)(ws + PG);
  bf16_t* ppP    = (bf16_t*)(ws + PP);
  bf16_t* ptP    = (bf16_t*)(ws + PT);
  bf16_t* w1bP   = (bf16_t*)(ws + W1B);
  float*  qwP    = (float*)(ws + QW);
  float*  scoreP = (float*)(ws + SCORE);
  float*  mpartP = (float*)(ws + MPART);
  float*  mprt2P = (float*)(ws + MPRT2);
  bf16_t* zpadP  = (bf16_t*)(ws + ZPAD);
  float*  zpartP = (float*)(ws + ZPART);
  float*  uP     = (float*)(ws + U);
  float*  ctxvP  = (float*)(ws + CTXV);
  float*  attvP  = (float*)(ws + ATTV);
  float*  yP     = (float*)(ws + Y);
  float*  shP    = (float*)(ws + SH);
  float*  c01P   = (float*)(ws + C01);
  float*  pmaxP  = (float*)(ws + PMAX);
  float*  mhP    = (float*)(ws + MH);
  float*  sinvP  = (float*)(ws + SINV);
  float*  spartP = (float*)(ws + SPART);
  float*  bmaxP  = (float*)(ws + BMAX);
  float*  mlP    = (float*)(ws + ML);
  float*  slinvP = (float*)(ws + SLINV);
  float*  lpartP = (float*)(ws + LPART);

  float* probsOut  = (float*)d_out;
  float* logitsOut = probsOut + A_TOTAL;

  // zero y + shalf + c01 (contiguous alloc region: 8192 + 256 + 256)
  hipMemsetAsync(yP, 0, 8704, stream);

  k_w1b16<<<1024, 256, 0, stream>>>(map_W1, sch_W1, w1bP);
  k_mean<<<2048, 256, 0, stream>>>(all_emb, mpartP);
  k_mean2<<<16, 256, 0, stream>>>(mpartP, mprt2P);
  k_front<<<1, 256, 0, stream>>>(mprt2P, qg_W1, qg_b1, qg_W2, qg_b2,
                                 Wq, bq, Wk, map_W2, sch_W2, qwP);

  // table projections: qubit+gate merged, qpu+time merged
  gemm_direct3<<<1024, 512, 0, stream>>>(
      qubit_emb, 65536, w1bP + 0 * 65536, nullptr, pqP, 512,
      gate_emb,  65536, w1bP + 2 * 65536, nullptr, pgP);
  gemm_direct3<<<9, 512, 0, stream>>>(
      qpu_emb, 64,   w1bP + 1 * 65536, map_b1, ppP, 1,
      time_tab, 1000, w1bP + 3 * 65536, sch_b1, ptP);

  // X = relu(gather sum) + fused scores (q in registers)
  k_gx<<<4096, 256, 0, stream>>>(
      pqP, ppP, map_qubit, map_qpu,
      pgP, ptP, sched_gate, sched_time,
      qwP, xP, scoreP, pmaxP);

  // softmax stats over scores
  k_smax2<<<1, 256, 0, stream>>>(pmaxP, mhP);
  k_ssum<<<256, 256, 0, stream>>>(scoreP, mhP, spartP);
  k_ssum2<<<1, 256, 0, stream>>>(spartP, sinvP);

  // weighted X sums per half -> tail chain (all row-parallel)
  k_u3<<<512, 256, 0, stream>>>(xP, scoreP, mhP, sinvP, yP, shP);
  k_u4<<<256, 256, 0, stream>>>(yP, shP, map_W2, sch_W2, map_b2, sch_b2, uP);
  k_ctx<<<256, 256, 0, stream>>>(uP, Wv, bv, ctxvP);
  k_att<<<256, 256, 0, stream>>>(ctxvP, Wo, bo, map_b2, sch_b2, attvP, c01P);
  k_z<<<32, 256, 0, stream>>>(map_W2, sch_W2, attvP, zpartP);
  k_zfin<<<1, 256, 0, stream>>>(zpartP, zpadP);

  // logits + global softmax
  k_logits3<<<1024, 256, 0, stream>>>(xP, zpadP, c01P, logitsOut, bmaxP);
  k_lred1<<<1, 256, 0, stream>>>(bmaxP, mlP);
  k_lsum<<<512, 256, 0, stream>>>(logitsOut, mlP, lpartP);
  k_lred2<<<1, 256, 0, stream>>>(lpartP, slinvP);
  k_probs<<<1024, 256, 0, stream>>>(logitsOut, mlP, slinvP, probsOut);
}